// Round 6
// baseline (5640.170 us; speedup 1.0000x reference)
//
#include <hip/hip_runtime.h>

#define DDIM 2048
#define BDIM 512
#define NELEM (BDIM * DDIM)
#define NV4 (NELEM / 4)
#define NW4 (DDIM * DDIM / 4)

#define SC_DT 0
#define SC_DONE 1
#define SC_ERR 2
#define SC_SP 3

#define TOLF 0.01f
#define MIN_DTF 0.1f
#define SPEED_TOLF 1e-3f

typedef _Float16 half8 __attribute__((ext_vector_type(8)));
typedef _Float16 half4v __attribute__((ext_vector_type(4)));
typedef float f32x4 __attribute__((ext_vector_type(4)));

__device__ __forceinline__ void glds16(const _Float16* g, _Float16* l) {
    __builtin_amdgcn_global_load_lds((__attribute__((address_space(1))) void*)g,
                                     (__attribute__((address_space(3))) void*)l, 16, 0, 0);
}

__device__ __forceinline__ void split_f16(float y, _Float16& h, _Float16& l) {
    h = (_Float16)y;
    l = (_Float16)(y - (float)h);
}

__device__ __forceinline__ float reflect_f(float v) {
    int i = (int)v;
    return ((i & 1) == 0) ? v : 1.0f - v;
}

// ---------------- init / conversion kernels ----------------

__global__ void wconv_kernel(const float* __restrict__ W, _Float16* __restrict__ Wh,
                             _Float16* __restrict__ Wl) {
    int tid = blockIdx.x * blockDim.x + threadIdx.x;
    const float4* Wv = (const float4*)W;
    for (int i = tid; i < NW4; i += gridDim.x * blockDim.x) {
        float4 v = Wv[i];
        half4v h, l;
        float vv[4] = {v.x, v.y, v.z, v.w};
#pragma unroll
        for (int q = 0; q < 4; ++q) {
            _Float16 hh, ll;
            split_f16(vv[q], hh, ll);
            h[q] = hh;
            l[q] = ll;
        }
        *(half4v*)&Wh[(size_t)i * 4] = h;
        *(half4v*)&Wl[(size_t)i * 4] = l;
    }
}

__global__ void init_kernel(const float* __restrict__ x0, float* __restrict__ x,
                            _Float16* __restrict__ Axh, _Float16* __restrict__ Axl,
                            float* __restrict__ scal) {
    int tid = blockIdx.x * blockDim.x + threadIdx.x;
    const float4* X0 = (const float4*)x0;
    float4* X = (float4*)x;
    for (int i = tid; i < NV4; i += gridDim.x * blockDim.x) {
        float4 v = X0[i];
        X[i] = v;
        half4v h, l;
        float vv[4] = {v.x, v.y, v.z, v.w};
#pragma unroll
        for (int q = 0; q < 4; ++q) {
            float y = reflect_f(vv[q]);
            _Float16 hh, ll;
            split_f16(y, hh, ll);
            h[q] = hh;
            l[q] = ll;
        }
        *(half4v*)&Axh[(size_t)i * 4] = h;
        *(half4v*)&Axl[(size_t)i * 4] = l;
    }
    if (tid == 0) {
        scal[SC_DT] = 0.1f;
        ((unsigned int*)scal)[SC_DONE] = 0u;
        scal[SC_ERR] = 0.0f;
        scal[SC_SP] = 0.0f;
        scal[8 + SC_ERR] = 0.0f;
        scal[8 + SC_SP] = 0.0f;
    }
}

// ---------------- fused stage GEMM (k-split-4, 16 waves, BK=32) ----------------
// kS = sign(xs_S) * (G(xs_S) @ W + bias), 3-pass split-f16 MFMA.
// All four operand matrices (Ah, Al, Wh, Wl) staged in LDS via global_load_lds
// with XOR chunk swizzle. 16 waves = 4 k-groups x (2x2 wave grid); 4 waves/SIMD
// for latency hiding. Partials summed via LDS with 4-way sub-fragment ownership.

#define MFMA_AC(a, b, c) c = __builtin_amdgcn_mfma_f32_16x16x32_f16(a, b, c, 0, 0, 0)

template <int S>
__global__ __launch_bounds__(1024, 4) void stage_kernel(
    const _Float16* __restrict__ Ah, const _Float16* __restrict__ Al,
    _Float16* __restrict__ Aoh, _Float16* __restrict__ Aol, const _Float16* __restrict__ Wh,
    const _Float16* __restrict__ Wl, const float* __restrict__ bias,
    const float* __restrict__ xg, const float* __restrict__ gk1, const float* __restrict__ gk2,
    const float* __restrict__ gk3, const float* __restrict__ gk4, const float* __restrict__ gk5,
    float* __restrict__ kout, float* __restrict__ x5out, float* __restrict__ scal) {
    __shared__ __align__(16) _Float16 lds[4][2][4][64 * 32];  // 128KB [grp][buf][Ah,Al,Wh,Wl][64r x 32k]
    __shared__ float serr[16], ssp[16];

    const int tid = threadIdx.x;
    const int li = tid & 63;
    const int wid = tid >> 6;  // 0..15
    const int g = wid >> 2;    // k-split group 0..3
    const int w4 = wid & 3;    // wave-in-group
    const int wm = w4 >> 1, wn = w4 & 1;

    // XCD-aware swizzle: 256 blocks = 8 XCDs x 32; each XCD = 4(m) x 8(n) super-tile
    const int bid = blockIdx.x;
    const int xcd = bid & 7, jj = bid >> 3;
    const int bm = (xcd & 1) * 4 + (jj & 3);
    const int bn = (xcd >> 1) * 8 + (jj >> 2);

    const int kbase = g * 512;  // this group's K range: [kbase, kbase+512)

    f32x4 acc00 = (f32x4)(0.0f), acc01 = (f32x4)(0.0f);
    f32x4 acc10 = (f32x4)(0.0f), acc11 = (f32x4)(0.0f);

    // staging coords: 256 chunks of 16B per 4KB matrix tile; this group's 4 waves
    // cover them. chunk c -> row c>>2, col-chunk (c&3), XOR-swizzled (involution).
    const int c = w4 * 64 + li;
    const int srow = c >> 2;
    const int schs = (c & 3) ^ (srow & 3);
    const size_t gaoff = (size_t)(bm * 64 + srow) * DDIM + schs * 8;
    const size_t gwoff = (size_t)(bn * 64 + srow) * DDIM + schs * 8;
    const int ldst = c * 8;  // lane-linear LDS dest (halfs)

    auto stage4 = [&](int buf, int k0) {
        glds16(Ah + gaoff + k0, &lds[g][buf][0][ldst]);
        glds16(Al + gaoff + k0, &lds[g][buf][1][ldst]);
        glds16(Wh + gwoff + k0, &lds[g][buf][2][ldst]);
        glds16(Wl + gwoff + k0, &lds[g][buf][3][ldst]);
    };

    auto rdfrag = [&](int buf, int mat, int rbase) -> half8 {
        int r = rbase + (li & 15);
        int cl = li >> 4;
        int off = r * 32 + ((cl ^ (r & 3)) << 3);
        return *(const half8*)&lds[g][buf][mat][off];
    };

    auto compute = [&](int buf) {
        half8 ah0 = rdfrag(buf, 0, wm * 32);
        half8 ah1 = rdfrag(buf, 0, wm * 32 + 16);
        half8 al0 = rdfrag(buf, 1, wm * 32);
        half8 al1 = rdfrag(buf, 1, wm * 32 + 16);
        half8 bh0 = rdfrag(buf, 2, wn * 32);
        half8 bh1 = rdfrag(buf, 2, wn * 32 + 16);
        half8 bl0 = rdfrag(buf, 3, wn * 32);
        half8 bl1 = rdfrag(buf, 3, wn * 32 + 16);
        __builtin_amdgcn_s_setprio(1);
        MFMA_AC(ah0, bh0, acc00);
        MFMA_AC(ah0, bh1, acc01);
        MFMA_AC(ah1, bh0, acc10);
        MFMA_AC(ah1, bh1, acc11);
        MFMA_AC(ah0, bl0, acc00);
        MFMA_AC(ah0, bl1, acc01);
        MFMA_AC(ah1, bl0, acc10);
        MFMA_AC(ah1, bl1, acc11);
        MFMA_AC(al0, bh0, acc00);
        MFMA_AC(al0, bh1, acc01);
        MFMA_AC(al1, bh0, acc10);
        MFMA_AC(al1, bh1, acc11);
        __builtin_amdgcn_s_setprio(0);
    };

    // --- pipelined K loop: 16 tiles of BK=32 per group, counted vmcnt ---
    stage4(0, kbase);
#pragma unroll 1
    for (int t = 0; t < 16; ++t) {
        if (t < 15) {
            stage4((t + 1) & 1, kbase + (t + 1) * 32);
            // 4 newest (tile t+1) may remain in flight; tile t's 4 are guaranteed done
            asm volatile("s_waitcnt vmcnt(4)" ::: "memory");
        } else {
            asm volatile("s_waitcnt vmcnt(0)" ::: "memory");
        }
        __builtin_amdgcn_sched_barrier(0);
        __builtin_amdgcn_s_barrier();
        compute(t & 1);
        __builtin_amdgcn_s_barrier();
    }

    // --- partial-sum exchange across the 4 k-groups ---
    // sub-fragment s = mi*2+ni is owned by group s; each wave ships the other 3.
    float4* xch = (float4*)&lds[0][0][0][0];  // 64 KB scratch (groups 0-1 buffers)
#pragma unroll
    for (int s = 0; s < 4; ++s) {
        if (s == g) continue;
        f32x4 v = (s == 0) ? acc00 : (s == 1) ? acc01 : (s == 2) ? acc10 : acc11;
        xch[((s * 4 + g) * 4 + w4) * 64 + li] = make_float4(v[0], v[1], v[2], v[3]);
    }
    __syncthreads();
    f32x4 fin = (g == 0) ? acc00 : (g == 1) ? acc01 : (g == 2) ? acc10 : acc11;
#pragma unroll
    for (int gp = 0; gp < 4; ++gp) {
        if (gp == g) continue;
        float4 p = xch[((g * 4 + gp) * 4 + w4) * 64 + li];
        fin[0] += p.x;
        fin[1] += p.y;
        fin[2] += p.z;
        fin[3] += p.w;
    }

    // --- fused epilogue: wave (g,w4) finalizes its owned 16x16 tile (4 elem/thread) ---
    const int mi = g >> 1, ni = g & 1;
    const float dt = scal[SC_DT];
    const int lrow = li >> 4, lcol = li & 15;
    const int n = bn * 64 + wn * 32 + ni * 16 + lcol;
    const float biasv = bias[n];
    float lerr = 0.0f, lsp = 0.0f;

#pragma unroll
    for (int r = 0; r < 4; ++r) {
        int m = bm * 64 + wm * 32 + mi * 16 + lrow * 4 + r;
        size_t idx = (size_t)m * DDIM + n;
        float accv = fin[r] + biasv;
        float xv = xg[idx];
        float lk1 = 0.f, lk2 = 0.f, lk3 = 0.f, lk4 = 0.f, lk5 = 0.f;
        if constexpr (S >= 2) lk1 = gk1[idx];
        if constexpr (S >= 3) lk2 = gk2[idx];
        if constexpr (S >= 4) lk3 = gk3[idx];
        if constexpr (S >= 5) lk4 = gk4[idx];
        if constexpr (S >= 6) lk5 = gk5[idx];
        // recompute this stage's xs for the reflect-sign
        float xs;
        if constexpr (S == 1) xs = xv;
        if constexpr (S == 2) xs = xv + dt * (0.25f * lk1);
        if constexpr (S == 3)
            xs = xv + dt * ((float)(3.0 / 32.0) * lk1 + (float)(9.0 / 32.0) * lk2);
        if constexpr (S == 4)
            xs = xv + dt * ((float)(1932.0 / 2197.0) * lk1 + (float)(-7200.0 / 2197.0) * lk2 +
                            (float)(7296.0 / 2197.0) * lk3);
        if constexpr (S == 5)
            xs = xv + dt * ((float)(439.0 / 216.0) * lk1 - 8.0f * lk2 +
                            (float)(3680.0 / 513.0) * lk3 + (float)(-845.0 / 4104.0) * lk4);
        if constexpr (S == 6)
            xs = xv + dt * ((float)(-8.0 / 27.0) * lk1 + 2.0f * lk2 +
                            (float)(-3544.0 / 2565.0) * lk3 + (float)(1859.0 / 4104.0) * lk4 +
                            (float)(-11.0 / 40.0) * lk5);
        float sgn = (((int)xs) & 1) ? -1.0f : 1.0f;
        float kv = sgn * accv;
        if constexpr (S < 6) {
            kout[idx] = kv;
            float xn;
            if constexpr (S == 1) xn = xv + dt * (0.25f * kv);
            if constexpr (S == 2)
                xn = xv + dt * ((float)(3.0 / 32.0) * lk1 + (float)(9.0 / 32.0) * kv);
            if constexpr (S == 3)
                xn = xv + dt * ((float)(1932.0 / 2197.0) * lk1 + (float)(-7200.0 / 2197.0) * lk2 +
                                (float)(7296.0 / 2197.0) * kv);
            if constexpr (S == 4)
                xn = xv + dt * ((float)(439.0 / 216.0) * lk1 - 8.0f * lk2 +
                                (float)(3680.0 / 513.0) * lk3 + (float)(-845.0 / 4104.0) * kv);
            if constexpr (S == 5)
                xn = xv + dt * ((float)(-8.0 / 27.0) * lk1 + 2.0f * lk2 +
                                (float)(-3544.0 / 2565.0) * lk3 + (float)(1859.0 / 4104.0) * lk4 +
                                (float)(-11.0 / 40.0) * kv);
            float y = reflect_f(xn);
            _Float16 hh, ll;
            split_f16(y, hh, ll);
            Aoh[idx] = hh;
            Aol[idx] = ll;
        } else {
            float x5 = xv + dt * ((float)(16.0 / 135.0) * lk1 + (float)(6656.0 / 12825.0) * lk3 +
                                  (float)(28561.0 / 56430.0) * lk4 + (float)(-9.0 / 50.0) * lk5 +
                                  (float)(2.0 / 55.0) * kv);
            float x4 = xv + dt * ((float)(25.0 / 216.0) * lk1 + (float)(1408.0 / 2565.0) * lk3 +
                                  (float)(2197.0 / 4104.0) * lk4 + (float)(-1.0 / 5.0) * lk5);
            lerr = fmaxf(lerr, fabsf(x5 - x4));
            lsp = fmaxf(lsp, fabsf(x5 - xv));
            x5out[idx] = x5;
        }
    }

    if constexpr (S == 6) {
#pragma unroll
        for (int off = 32; off > 0; off >>= 1) {
            lerr = fmaxf(lerr, __shfl_down(lerr, off));
            lsp = fmaxf(lsp, __shfl_down(lsp, off));
        }
        if (li == 0) {
            serr[wid] = lerr;
            ssp[wid] = lsp;
        }
        __syncthreads();
        if (tid == 0) {
            float e = serr[0], s = ssp[0];
#pragma unroll
            for (int w = 1; w < 16; ++w) {
                e = fmaxf(e, serr[w]);
                s = fmaxf(s, ssp[w]);
            }
            atomicMax((unsigned int*)&scal[SC_ERR], __float_as_uint(e));
            atomicMax((unsigned int*)&scal[SC_SP], __float_as_uint(s));
        }
    }
}

// ---------------- fused scalar update + commit ----------------
// Every block recomputes the deterministic accept decision from the read-parity
// scalar slots; block 0 writes the next-parity slots. Rejected steps skip all
// x/A traffic.

__global__ void commit_fused(float* __restrict__ x, const float* __restrict__ x5,
                             _Float16* __restrict__ Axh, _Float16* __restrict__ Axl,
                             const float* __restrict__ scal_rd, float* __restrict__ scal_wr) {
    float dt = scal_rd[SC_DT];
    float err = scal_rd[SC_ERR];
    float sp = scal_rd[SC_SP];
    unsigned int done = ((const unsigned int*)scal_rd)[SC_DONE];
    bool accept = err < TOLF;
    bool step = accept && (done == 0u);
    float speed = sp / dt;
    unsigned int done_new = (done || (step && speed < SPEED_TOLF)) ? 1u : 0u;
    float scale = 0.9f * powf(TOLF / (err + 1e-12f), 0.2f);
    scale = fminf(fmaxf(scale, 0.1f), 4.0f);
    float dtn = fmaxf(dt * scale, MIN_DTF);
    if (blockIdx.x == 0 && threadIdx.x == 0) {
        scal_wr[SC_DT] = done ? dt : dtn;
        ((unsigned int*)scal_wr)[SC_DONE] = done_new;
        scal_wr[SC_ERR] = 0.0f;
        scal_wr[SC_SP] = 0.0f;
    }
    if (!step) return;  // x unchanged; Ax split still valid
    int tid = blockIdx.x * blockDim.x + threadIdx.x;
    float4* X = (float4*)x;
    const float4* X5 = (const float4*)x5;
    for (int i = tid; i < NV4; i += gridDim.x * blockDim.x) {
        float4 v = X5[i];
        X[i] = v;
        half4v h, l;
        float vv[4] = {v.x, v.y, v.z, v.w};
#pragma unroll
        for (int q = 0; q < 4; ++q) {
            float y = reflect_f(vv[q]);
            _Float16 hh, ll;
            split_f16(y, hh, ll);
            h[q] = hh;
            l[q] = ll;
        }
        *(half4v*)&Axh[(size_t)i * 4] = h;
        *(half4v*)&Axl[(size_t)i * 4] = l;
    }
}

// ---------------- launch ----------------

extern "C" void kernel_launch(void* const* d_in, const int* in_sizes, int n_in, void* d_out,
                              int out_size, void* d_ws, size_t ws_size, hipStream_t stream) {
    const float* x0 = (const float*)d_in[0];
    const float* W = (const float*)d_in[1];
    const float* bias = (const float*)d_in[2];
    float* x = (float*)d_out;

    float* ws = (float*)d_ws;
    float* k1 = ws + 0 * (size_t)NELEM;
    float* k2 = ws + 1 * (size_t)NELEM;
    float* k3 = ws + 2 * (size_t)NELEM;
    float* k4 = ws + 3 * (size_t)NELEM;
    float* k5 = ws + 4 * (size_t)NELEM;
    float* x5 = ws + 5 * (size_t)NELEM;
    float* scal = ws + 6 * (size_t)NELEM;  // 2 parity slots x 8 floats
    _Float16* hb = (_Float16*)(ws + 6 * (size_t)NELEM + 64);
    _Float16* Axh = hb + 0 * (size_t)NELEM;
    _Float16* Axl = hb + 1 * (size_t)NELEM;
    _Float16* P0h = hb + 2 * (size_t)NELEM;
    _Float16* P0l = hb + 3 * (size_t)NELEM;
    _Float16* P1h = hb + 4 * (size_t)NELEM;
    _Float16* P1l = hb + 5 * (size_t)NELEM;
    _Float16* Wh = hb + 6 * (size_t)NELEM;
    _Float16* Wl = Wh + (size_t)DDIM * DDIM;

    wconv_kernel<<<2048, 256, 0, stream>>>(W, Wh, Wl);
    init_kernel<<<1024, 256, 0, stream>>>(x0, x, Axh, Axl, scal);

    for (int it = 0; it < 32; ++it) {
        float* sp = scal + (it & 1) * 8;
        float* sn = scal + ((it + 1) & 1) * 8;
        stage_kernel<1><<<256, 1024, 0, stream>>>(Axh, Axl, P0h, P0l, Wh, Wl, bias, x, k1, k2,
                                                  k3, k4, k5, k1, x5, sp);
        stage_kernel<2><<<256, 1024, 0, stream>>>(P0h, P0l, P1h, P1l, Wh, Wl, bias, x, k1, k2,
                                                  k3, k4, k5, k2, x5, sp);
        stage_kernel<3><<<256, 1024, 0, stream>>>(P1h, P1l, P0h, P0l, Wh, Wl, bias, x, k1, k2,
                                                  k3, k4, k5, k3, x5, sp);
        stage_kernel<4><<<256, 1024, 0, stream>>>(P0h, P0l, P1h, P1l, Wh, Wl, bias, x, k1, k2,
                                                  k3, k4, k5, k4, x5, sp);
        stage_kernel<5><<<256, 1024, 0, stream>>>(P1h, P1l, P0h, P0l, Wh, Wl, bias, x, k1, k2,
                                                  k3, k4, k5, k5, x5, sp);
        stage_kernel<6><<<256, 1024, 0, stream>>>(P0h, P0l, P1h, P1l, Wh, Wl, bias, x, k1, k2,
                                                  k3, k4, k5, k1, x5, sp);
        commit_fused<<<1024, 256, 0, stream>>>(x, x5, Axh, Axl, sp, sn);
    }
}

// Round 7
// 4555.822 us; speedup vs baseline: 1.2380x; 1.2380x over previous
//
#include <hip/hip_runtime.h>

#define DDIM 2048
#define BDIM 512
#define NELEM (BDIM * DDIM)
#define NV4 (NELEM / 4)
#define NW4 (DDIM * DDIM / 4)

#define SC_DT 0
#define SC_DONE 1
#define SC_ERR 2
#define SC_SP 3

#define TOLF 0.01f
#define MIN_DTF 0.1f
#define SPEED_TOLF 1e-3f

typedef _Float16 half8 __attribute__((ext_vector_type(8)));
typedef _Float16 half4v __attribute__((ext_vector_type(4)));
typedef float f32x4 __attribute__((ext_vector_type(4)));

__device__ __forceinline__ void glds16(const _Float16* g, _Float16* l) {
    __builtin_amdgcn_global_load_lds((__attribute__((address_space(1))) void*)g,
                                     (__attribute__((address_space(3))) void*)l, 16, 0, 0);
}

__device__ __forceinline__ void split_f16(float y, _Float16& h, _Float16& l) {
    h = (_Float16)y;
    l = (_Float16)(y - (float)h);
}

__device__ __forceinline__ float reflect_f(float v) {
    int i = (int)v;
    return ((i & 1) == 0) ? v : 1.0f - v;
}

// ---------------- init / conversion kernels ----------------

__global__ void wconv_kernel(const float* __restrict__ W, _Float16* __restrict__ Wh,
                             _Float16* __restrict__ Wl) {
    int tid = blockIdx.x * blockDim.x + threadIdx.x;
    const float4* Wv = (const float4*)W;
    for (int i = tid; i < NW4; i += gridDim.x * blockDim.x) {
        float4 v = Wv[i];
        half4v h, l;
        float vv[4] = {v.x, v.y, v.z, v.w};
#pragma unroll
        for (int q = 0; q < 4; ++q) {
            _Float16 hh, ll;
            split_f16(vv[q], hh, ll);
            h[q] = hh;
            l[q] = ll;
        }
        *(half4v*)&Wh[(size_t)i * 4] = h;
        *(half4v*)&Wl[(size_t)i * 4] = l;
    }
}

__global__ void init_kernel(const float* __restrict__ x0, float* __restrict__ x,
                            _Float16* __restrict__ Axh, _Float16* __restrict__ Axl,
                            float* __restrict__ scal) {
    int tid = blockIdx.x * blockDim.x + threadIdx.x;
    const float4* X0 = (const float4*)x0;
    float4* X = (float4*)x;
    for (int i = tid; i < NV4; i += gridDim.x * blockDim.x) {
        float4 v = X0[i];
        X[i] = v;
        half4v h, l;
        float vv[4] = {v.x, v.y, v.z, v.w};
#pragma unroll
        for (int q = 0; q < 4; ++q) {
            float y = reflect_f(vv[q]);
            _Float16 hh, ll;
            split_f16(y, hh, ll);
            h[q] = hh;
            l[q] = ll;
        }
        *(half4v*)&Axh[(size_t)i * 4] = h;
        *(half4v*)&Axl[(size_t)i * 4] = l;
    }
    if (tid == 0) {
        scal[SC_DT] = 0.1f;
        ((unsigned int*)scal)[SC_DONE] = 0u;
        scal[SC_ERR] = 0.0f;
        scal[SC_SP] = 0.0f;
        scal[8 + SC_ERR] = 0.0f;
        scal[8 + SC_SP] = 0.0f;
    }
}

// ---------------- fused stage GEMM (K-split-2, 8 waves, 1-barrier 2-phase) ----------------
// kS = sign(xs_S) * (G(xs_S) @ W + bias), 3-pass split-f16 MFMA.
// All four operands (Ah, Al, Wh, Wl) staged via global_load_lds with XOR chunk
// swizzle. Schedule per k-tile: STAGE(next) issued first, then ds_read+MFMA on
// current, then vmcnt(0)+single barrier (T3 minimum-2-phase: write-after-read
// safe because next's buffer was last read in compute(t-1), which finished
// before the barrier we just crossed; vmcnt-before-barrier publishes).

template <int S>
__global__ __launch_bounds__(512, 2) void stage_kernel(
    const _Float16* __restrict__ Ah, const _Float16* __restrict__ Al,
    _Float16* __restrict__ Aoh, _Float16* __restrict__ Aol, const _Float16* __restrict__ Wh,
    const _Float16* __restrict__ Wl, const float* __restrict__ bias,
    const float* __restrict__ xg, const float* __restrict__ gk1, const float* __restrict__ gk2,
    const float* __restrict__ gk3, const float* __restrict__ gk4, const float* __restrict__ gk5,
    float* __restrict__ kout, float* __restrict__ x5out, float* __restrict__ scal) {
    __shared__ __align__(16) _Float16 lds[2][2][4][64 * 64];  // [kgroup][buf][Ah,Al,Wh,Wl][...]
    __shared__ float serr[8], ssp[8];

    const int tid = threadIdx.x;
    const int li = tid & 63;
    const int wid = tid >> 6;  // 0..7
    const int g = wid >> 2;    // k-split group
    const int w4 = wid & 3;    // wave-in-group
    const int wm = w4 >> 1, wn = w4 & 1;

    // XCD-aware swizzle: 256 blocks = 8 XCDs x 32; each XCD = 4(m) x 8(n) super-tile
    const int bid = blockIdx.x;
    const int xcd = bid & 7, jj = bid >> 3;
    const int bm = (xcd & 1) * 4 + (jj & 3);
    const int bn = (xcd >> 1) * 8 + (jj >> 2);

    const int kbase = g * 1024;

    f32x4 acc00 = (f32x4)(0.0f), acc01 = (f32x4)(0.0f);
    f32x4 acc10 = (f32x4)(0.0f), acc11 = (f32x4)(0.0f);

    // staging: 4 matrices, 8KB each; wave w covers 1KB chunks {w, w+4} (8 glds/thread)
    auto stage4 = [&](int buf, int k0) {
#pragma unroll
        for (int cc = 0; cc < 2; ++cc) {
            int c = w4 + cc * 4;
            int row = c * 8 + (li >> 3);
            int clog = (li & 7) ^ (row & 7);  // XOR chunk swizzle (involution)
            int ga = (bm * 64 + row) * DDIM + k0 + clog * 8;
            int gw = (bn * 64 + row) * DDIM + k0 + clog * 8;
            int lo_ = c * 512 + li * 8;
            glds16(Ah + ga, &lds[g][buf][0][lo_]);
            glds16(Al + ga, &lds[g][buf][1][lo_]);
            glds16(Wh + gw, &lds[g][buf][2][lo_]);
            glds16(Wl + gw, &lds[g][buf][3][lo_]);
        }
    };

    auto rdfrag = [&](int buf, int mat, int rbase, int ks) -> half8 {
        int r = rbase + (li & 15);
        int cl = ks * 4 + (li >> 4);
        int off = r * 64 + ((cl ^ (r & 7)) << 3);
        return *(const half8*)&lds[g][buf][mat][off];
    };

    auto compute = [&](int buf) {
#pragma unroll
        for (int ks = 0; ks < 2; ++ks) {
            half8 ah0 = rdfrag(buf, 0, wm * 32, ks);
            half8 ah1 = rdfrag(buf, 0, wm * 32 + 16, ks);
            half8 al0 = rdfrag(buf, 1, wm * 32, ks);
            half8 al1 = rdfrag(buf, 1, wm * 32 + 16, ks);
            half8 bh0 = rdfrag(buf, 2, wn * 32, ks);
            half8 bh1 = rdfrag(buf, 2, wn * 32 + 16, ks);
            half8 bl0 = rdfrag(buf, 3, wn * 32, ks);
            half8 bl1 = rdfrag(buf, 3, wn * 32 + 16, ks);
            __builtin_amdgcn_s_setprio(1);
            acc00 = __builtin_amdgcn_mfma_f32_16x16x32_f16(ah0, bh0, acc00, 0, 0, 0);
            acc01 = __builtin_amdgcn_mfma_f32_16x16x32_f16(ah0, bh1, acc01, 0, 0, 0);
            acc10 = __builtin_amdgcn_mfma_f32_16x16x32_f16(ah1, bh0, acc10, 0, 0, 0);
            acc11 = __builtin_amdgcn_mfma_f32_16x16x32_f16(ah1, bh1, acc11, 0, 0, 0);
            acc00 = __builtin_amdgcn_mfma_f32_16x16x32_f16(ah0, bl0, acc00, 0, 0, 0);
            acc01 = __builtin_amdgcn_mfma_f32_16x16x32_f16(ah0, bl1, acc01, 0, 0, 0);
            acc10 = __builtin_amdgcn_mfma_f32_16x16x32_f16(ah1, bl0, acc10, 0, 0, 0);
            acc11 = __builtin_amdgcn_mfma_f32_16x16x32_f16(ah1, bl1, acc11, 0, 0, 0);
            acc00 = __builtin_amdgcn_mfma_f32_16x16x32_f16(al0, bh0, acc00, 0, 0, 0);
            acc01 = __builtin_amdgcn_mfma_f32_16x16x32_f16(al0, bh1, acc01, 0, 0, 0);
            acc10 = __builtin_amdgcn_mfma_f32_16x16x32_f16(al1, bh0, acc10, 0, 0, 0);
            acc11 = __builtin_amdgcn_mfma_f32_16x16x32_f16(al1, bh1, acc11, 0, 0, 0);
            __builtin_amdgcn_s_setprio(0);
        }
    };

    // --- 1-barrier 2-phase pipelined K loop: 16 k-tiles of BK=64 per group ---
    stage4(0, kbase);
    asm volatile("s_waitcnt vmcnt(0)" ::: "memory");
    __builtin_amdgcn_s_barrier();
#pragma unroll 2
    for (int t = 0; t < 16; ++t) {
        if (t < 15) stage4((t + 1) & 1, kbase + (t + 1) * 64);
        compute(t & 1);
        asm volatile("s_waitcnt vmcnt(0)" ::: "memory");
        __builtin_amdgcn_sched_barrier(0);
        __builtin_amdgcn_s_barrier();
    }

    // --- partial-sum exchange: group g keeps the mi==g band, ships the other ---
    f32x4 ship0 = (g == 0) ? acc10 : acc00;
    f32x4 ship1 = (g == 0) ? acc11 : acc01;
    f32x4 keep0 = (g == 0) ? acc00 : acc10;
    f32x4 keep1 = (g == 0) ? acc01 : acc11;
    float4* xch = (float4*)&lds[0][0][0][0];
    {
        int slot0 = ((g * 4 + w4) * 2 + 0) * 64 + li;
        int slot1 = ((g * 4 + w4) * 2 + 1) * 64 + li;
        xch[slot0] = make_float4(ship0[0], ship0[1], ship0[2], ship0[3]);
        xch[slot1] = make_float4(ship1[0], ship1[1], ship1[2], ship1[3]);
    }
    __syncthreads();
    f32x4 fin[2];
    {
        int slot0 = (((1 - g) * 4 + w4) * 2 + 0) * 64 + li;
        int slot1 = (((1 - g) * 4 + w4) * 2 + 1) * 64 + li;
        float4 p0 = xch[slot0];
        float4 p1 = xch[slot1];
        keep0[0] += p0.x; keep0[1] += p0.y; keep0[2] += p0.z; keep0[3] += p0.w;
        keep1[0] += p1.x; keep1[1] += p1.y; keep1[2] += p1.z; keep1[3] += p1.w;
        fin[0] = keep0;
        fin[1] = keep1;
    }

    // --- fused epilogue: each thread finalizes 8 elems (rows wm*32+g*16+..) ---
    const float dt = scal[SC_DT];
    const int lrow = li >> 4, lcol = li & 15;
    const float bias0 = bias[bn * 64 + wn * 32 + lcol];
    const float bias1 = bias[bn * 64 + wn * 32 + 16 + lcol];
    float lerr = 0.0f, lsp = 0.0f;

#pragma unroll
    for (int r = 0; r < 4; ++r) {
        int m = bm * 64 + wm * 32 + g * 16 + lrow * 4 + r;
        size_t base = (size_t)m * DDIM;
#pragma unroll
        for (int ni = 0; ni < 2; ++ni) {
            int n = bn * 64 + wn * 32 + ni * 16 + lcol;
            size_t idx = base + n;
            float accv = fin[ni][r] + (ni == 0 ? bias0 : bias1);
            float xv = xg[idx];
            float lk1 = 0.f, lk2 = 0.f, lk3 = 0.f, lk4 = 0.f, lk5 = 0.f;
            if constexpr (S >= 2) lk1 = gk1[idx];
            if constexpr (S >= 3) lk2 = gk2[idx];
            if constexpr (S >= 4) lk3 = gk3[idx];
            if constexpr (S >= 5) lk4 = gk4[idx];
            if constexpr (S >= 6) lk5 = gk5[idx];
            float xs;
            if constexpr (S == 1) xs = xv;
            if constexpr (S == 2) xs = xv + dt * (0.25f * lk1);
            if constexpr (S == 3)
                xs = xv + dt * ((float)(3.0 / 32.0) * lk1 + (float)(9.0 / 32.0) * lk2);
            if constexpr (S == 4)
                xs = xv + dt * ((float)(1932.0 / 2197.0) * lk1 + (float)(-7200.0 / 2197.0) * lk2 +
                                (float)(7296.0 / 2197.0) * lk3);
            if constexpr (S == 5)
                xs = xv + dt * ((float)(439.0 / 216.0) * lk1 - 8.0f * lk2 +
                                (float)(3680.0 / 513.0) * lk3 + (float)(-845.0 / 4104.0) * lk4);
            if constexpr (S == 6)
                xs = xv + dt * ((float)(-8.0 / 27.0) * lk1 + 2.0f * lk2 +
                                (float)(-3544.0 / 2565.0) * lk3 + (float)(1859.0 / 4104.0) * lk4 +
                                (float)(-11.0 / 40.0) * lk5);
            float sgn = (((int)xs) & 1) ? -1.0f : 1.0f;
            float kv = sgn * accv;
            if constexpr (S < 6) {
                kout[idx] = kv;
                float xn;
                if constexpr (S == 1) xn = xv + dt * (0.25f * kv);
                if constexpr (S == 2)
                    xn = xv + dt * ((float)(3.0 / 32.0) * lk1 + (float)(9.0 / 32.0) * kv);
                if constexpr (S == 3)
                    xn = xv + dt * ((float)(1932.0 / 2197.0) * lk1 +
                                    (float)(-7200.0 / 2197.0) * lk2 + (float)(7296.0 / 2197.0) * kv);
                if constexpr (S == 4)
                    xn = xv + dt * ((float)(439.0 / 216.0) * lk1 - 8.0f * lk2 +
                                    (float)(3680.0 / 513.0) * lk3 + (float)(-845.0 / 4104.0) * kv);
                if constexpr (S == 5)
                    xn = xv + dt * ((float)(-8.0 / 27.0) * lk1 + 2.0f * lk2 +
                                    (float)(-3544.0 / 2565.0) * lk3 +
                                    (float)(1859.0 / 4104.0) * lk4 + (float)(-11.0 / 40.0) * kv);
                float y = reflect_f(xn);
                _Float16 hh, ll;
                split_f16(y, hh, ll);
                Aoh[idx] = hh;
                Aol[idx] = ll;
            } else {
                float x5 = xv + dt * ((float)(16.0 / 135.0) * lk1 + (float)(6656.0 / 12825.0) * lk3 +
                                      (float)(28561.0 / 56430.0) * lk4 + (float)(-9.0 / 50.0) * lk5 +
                                      (float)(2.0 / 55.0) * kv);
                float x4 = xv + dt * ((float)(25.0 / 216.0) * lk1 + (float)(1408.0 / 2565.0) * lk3 +
                                      (float)(2197.0 / 4104.0) * lk4 + (float)(-1.0 / 5.0) * lk5);
                lerr = fmaxf(lerr, fabsf(x5 - x4));
                lsp = fmaxf(lsp, fabsf(x5 - xv));
                x5out[idx] = x5;
            }
        }
    }

    if constexpr (S == 6) {
#pragma unroll
        for (int off = 32; off > 0; off >>= 1) {
            lerr = fmaxf(lerr, __shfl_down(lerr, off));
            lsp = fmaxf(lsp, __shfl_down(lsp, off));
        }
        if (li == 0) {
            serr[wid] = lerr;
            ssp[wid] = lsp;
        }
        __syncthreads();
        if (tid == 0) {
            float e = serr[0], s = ssp[0];
#pragma unroll
            for (int w = 1; w < 8; ++w) {
                e = fmaxf(e, serr[w]);
                s = fmaxf(s, ssp[w]);
            }
            atomicMax((unsigned int*)&scal[SC_ERR], __float_as_uint(e));
            atomicMax((unsigned int*)&scal[SC_SP], __float_as_uint(s));
        }
    }
}

// ---------------- fused scalar update + commit ----------------
// Every block recomputes the deterministic accept decision from the read-parity
// scalar slots; block 0 writes the next-parity slots. Rejected steps skip all
// x/A traffic (x and the Ax split stay valid).

__global__ void commit_fused(float* __restrict__ x, const float* __restrict__ x5,
                             _Float16* __restrict__ Axh, _Float16* __restrict__ Axl,
                             const float* __restrict__ scal_rd, float* __restrict__ scal_wr) {
    float dt = scal_rd[SC_DT];
    float err = scal_rd[SC_ERR];
    float sp = scal_rd[SC_SP];
    unsigned int done = ((const unsigned int*)scal_rd)[SC_DONE];
    bool accept = err < TOLF;
    bool step = accept && (done == 0u);
    float speed = sp / dt;
    unsigned int done_new = (done || (step && speed < SPEED_TOLF)) ? 1u : 0u;
    float scale = 0.9f * powf(TOLF / (err + 1e-12f), 0.2f);
    scale = fminf(fmaxf(scale, 0.1f), 4.0f);
    float dtn = fmaxf(dt * scale, MIN_DTF);
    if (blockIdx.x == 0 && threadIdx.x == 0) {
        scal_wr[SC_DT] = done ? dt : dtn;
        ((unsigned int*)scal_wr)[SC_DONE] = done_new;
        scal_wr[SC_ERR] = 0.0f;
        scal_wr[SC_SP] = 0.0f;
    }
    if (!step) return;  // x unchanged; Ax split still valid
    int tid = blockIdx.x * blockDim.x + threadIdx.x;
    float4* X = (float4*)x;
    const float4* X5 = (const float4*)x5;
    for (int i = tid; i < NV4; i += gridDim.x * blockDim.x) {
        float4 v = X5[i];
        X[i] = v;
        half4v h, l;
        float vv[4] = {v.x, v.y, v.z, v.w};
#pragma unroll
        for (int q = 0; q < 4; ++q) {
            float y = reflect_f(vv[q]);
            _Float16 hh, ll;
            split_f16(y, hh, ll);
            h[q] = hh;
            l[q] = ll;
        }
        *(half4v*)&Axh[(size_t)i * 4] = h;
        *(half4v*)&Axl[(size_t)i * 4] = l;
    }
}

// ---------------- launch ----------------

extern "C" void kernel_launch(void* const* d_in, const int* in_sizes, int n_in, void* d_out,
                              int out_size, void* d_ws, size_t ws_size, hipStream_t stream) {
    const float* x0 = (const float*)d_in[0];
    const float* W = (const float*)d_in[1];
    const float* bias = (const float*)d_in[2];
    float* x = (float*)d_out;

    float* ws = (float*)d_ws;
    float* k1 = ws + 0 * (size_t)NELEM;
    float* k2 = ws + 1 * (size_t)NELEM;
    float* k3 = ws + 2 * (size_t)NELEM;
    float* k4 = ws + 3 * (size_t)NELEM;
    float* k5 = ws + 4 * (size_t)NELEM;
    float* x5 = ws + 5 * (size_t)NELEM;
    float* scal = ws + 6 * (size_t)NELEM;  // 2 parity slots x 8 floats
    _Float16* hb = (_Float16*)(ws + 6 * (size_t)NELEM + 64);
    _Float16* Axh = hb + 0 * (size_t)NELEM;
    _Float16* Axl = hb + 1 * (size_t)NELEM;
    _Float16* P0h = hb + 2 * (size_t)NELEM;
    _Float16* P0l = hb + 3 * (size_t)NELEM;
    _Float16* P1h = hb + 4 * (size_t)NELEM;
    _Float16* P1l = hb + 5 * (size_t)NELEM;
    _Float16* Wh = hb + 6 * (size_t)NELEM;
    _Float16* Wl = Wh + (size_t)DDIM * DDIM;

    wconv_kernel<<<2048, 256, 0, stream>>>(W, Wh, Wl);
    init_kernel<<<1024, 256, 0, stream>>>(x0, x, Axh, Axl, scal);

    for (int it = 0; it < 32; ++it) {
        float* sp = scal + (it & 1) * 8;
        float* sn = scal + ((it + 1) & 1) * 8;
        stage_kernel<1><<<256, 512, 0, stream>>>(Axh, Axl, P0h, P0l, Wh, Wl, bias, x, k1, k2, k3,
                                                 k4, k5, k1, x5, sp);
        stage_kernel<2><<<256, 512, 0, stream>>>(P0h, P0l, P1h, P1l, Wh, Wl, bias, x, k1, k2, k3,
                                                 k4, k5, k2, x5, sp);
        stage_kernel<3><<<256, 512, 0, stream>>>(P1h, P1l, P0h, P0l, Wh, Wl, bias, x, k1, k2, k3,
                                                 k4, k5, k3, x5, sp);
        stage_kernel<4><<<256, 512, 0, stream>>>(P0h, P0l, P1h, P1l, Wh, Wl, bias, x, k1, k2, k3,
                                                 k4, k5, k4, x5, sp);
        stage_kernel<5><<<256, 512, 0, stream>>>(P1h, P1l, P0h, P0l, Wh, Wl, bias, x, k1, k2, k3,
                                                 k4, k5, k5, x5, sp);
        stage_kernel<6><<<256, 512, 0, stream>>>(P0h, P0l, P1h, P1l, Wh, Wl, bias, x, k1, k2, k3,
                                                 k4, k5, k1, x5, sp);
        commit_fused<<<1024, 256, 0, stream>>>(x, x5, Axh, Axl, sp, sn);
    }
}

// Round 8
// 4206.596 us; speedup vs baseline: 1.3408x; 1.0830x over previous
//
#include <hip/hip_runtime.h>

#define DDIM 2048
#define BDIM 512
#define NELEM (BDIM * DDIM)
#define NV4 (NELEM / 4)
#define NW4 (DDIM * DDIM / 4)

#define SC_DT 0
#define SC_DONE 1
#define SC_ERR 2
#define SC_SP 3

#define TOLF 0.01f
#define MIN_DTF 0.1f
#define SPEED_TOLF 1e-3f

typedef _Float16 half8 __attribute__((ext_vector_type(8)));
typedef _Float16 half4v __attribute__((ext_vector_type(4)));
typedef float f32x4 __attribute__((ext_vector_type(4)));

__device__ __forceinline__ void glds16(const _Float16* g, _Float16* l) {
    __builtin_amdgcn_global_load_lds((__attribute__((address_space(1))) void*)g,
                                     (__attribute__((address_space(3))) void*)l, 16, 0, 0);
}

__device__ __forceinline__ void split_f16(float y, _Float16& h, _Float16& l) {
    h = (_Float16)y;
    l = (_Float16)(y - (float)h);
}

__device__ __forceinline__ float reflect_f(float v) {
    int i = (int)v;
    return ((i & 1) == 0) ? v : 1.0f - v;
}

// ---------------- init / conversion kernels ----------------

__global__ void wconv_kernel(const float* __restrict__ W, _Float16* __restrict__ Wh,
                             _Float16* __restrict__ Wl) {
    int tid = blockIdx.x * blockDim.x + threadIdx.x;
    const float4* Wv = (const float4*)W;
    for (int i = tid; i < NW4; i += gridDim.x * blockDim.x) {
        float4 v = Wv[i];
        half4v h, l;
        float vv[4] = {v.x, v.y, v.z, v.w};
#pragma unroll
        for (int q = 0; q < 4; ++q) {
            _Float16 hh, ll;
            split_f16(vv[q], hh, ll);
            h[q] = hh;
            l[q] = ll;
        }
        *(half4v*)&Wh[(size_t)i * 4] = h;
        *(half4v*)&Wl[(size_t)i * 4] = l;
    }
}

__global__ void init_kernel(const float* __restrict__ x0, float* __restrict__ x,
                            _Float16* __restrict__ Axh, _Float16* __restrict__ Axl,
                            float* __restrict__ scal) {
    int tid = blockIdx.x * blockDim.x + threadIdx.x;
    const float4* X0 = (const float4*)x0;
    float4* X = (float4*)x;
    for (int i = tid; i < NV4; i += gridDim.x * blockDim.x) {
        float4 v = X0[i];
        X[i] = v;
        half4v h, l;
        float vv[4] = {v.x, v.y, v.z, v.w};
#pragma unroll
        for (int q = 0; q < 4; ++q) {
            float y = reflect_f(vv[q]);
            _Float16 hh, ll;
            split_f16(y, hh, ll);
            h[q] = hh;
            l[q] = ll;
        }
        *(half4v*)&Axh[(size_t)i * 4] = h;
        *(half4v*)&Axl[(size_t)i * 4] = l;
    }
    if (tid == 0) {
        scal[SC_DT] = 0.1f;
        ((unsigned int*)scal)[SC_DONE] = 0u;
        scal[SC_ERR] = 0.0f;
        scal[SC_SP] = 0.0f;
        scal[8 + SC_ERR] = 0.0f;
        scal[8 + SC_SP] = 0.0f;
    }
}

// ---------------- fused stage GEMM (r3-exact: K-split-2, 8 waves, vmcnt(8), 2 barriers) ----
// kS = sign(xs_S) * (G(xs_S) @ W + bias), 3-pass split-f16 MFMA.
// All four operands (Ah, Al, Wh, Wl) staged via global_load_lds with XOR chunk
// swizzle. Schedule per k-tile (measured best, r3=4138us): stage(t+1) first,
// counted s_waitcnt vmcnt(8) (waits tile t only, t+1 stays in flight), barrier,
// compute(t), barrier.

template <int S>
__global__ __launch_bounds__(512, 2) void stage_kernel(
    const _Float16* __restrict__ Ah, const _Float16* __restrict__ Al,
    _Float16* __restrict__ Aoh, _Float16* __restrict__ Aol, const _Float16* __restrict__ Wh,
    const _Float16* __restrict__ Wl, const float* __restrict__ bias,
    const float* __restrict__ xg, const float* __restrict__ gk1, const float* __restrict__ gk2,
    const float* __restrict__ gk3, const float* __restrict__ gk4, const float* __restrict__ gk5,
    float* __restrict__ kout, float* __restrict__ x5out, float* __restrict__ scal) {
    __shared__ __align__(16) _Float16 lds[2][2][4][64 * 64];  // [kgroup][buf][Ah,Al,Wh,Wl][...]
    __shared__ float serr[8], ssp[8];

    const int tid = threadIdx.x;
    const int li = tid & 63;
    const int wid = tid >> 6;  // 0..7
    const int g = wid >> 2;    // k-split group
    const int w4 = wid & 3;    // wave-in-group
    const int wm = w4 >> 1, wn = w4 & 1;

    // XCD-aware swizzle: 256 blocks = 8 XCDs x 32; each XCD = 4(m) x 8(n) super-tile
    const int bid = blockIdx.x;
    const int xcd = bid & 7, jj = bid >> 3;
    const int bm = (xcd & 1) * 4 + (jj & 3);
    const int bn = (xcd >> 1) * 8 + (jj >> 2);

    const int kbase = g * 1024;

    f32x4 acc00 = (f32x4)(0.0f), acc01 = (f32x4)(0.0f);
    f32x4 acc10 = (f32x4)(0.0f), acc11 = (f32x4)(0.0f);

    // staging: 4 matrices, 8KB each; wave w covers 1KB chunks {w, w+4} (8 glds/thread)
    auto stage4 = [&](int buf, int k0) {
#pragma unroll
        for (int cc = 0; cc < 2; ++cc) {
            int c = w4 + cc * 4;
            int row = c * 8 + (li >> 3);
            int clog = (li & 7) ^ (row & 7);  // XOR chunk swizzle (involution)
            int ga = (bm * 64 + row) * DDIM + k0 + clog * 8;
            int gw = (bn * 64 + row) * DDIM + k0 + clog * 8;
            int lo_ = c * 512 + li * 8;
            glds16(Ah + ga, &lds[g][buf][0][lo_]);
            glds16(Al + ga, &lds[g][buf][1][lo_]);
            glds16(Wh + gw, &lds[g][buf][2][lo_]);
            glds16(Wl + gw, &lds[g][buf][3][lo_]);
        }
    };

    auto rdfrag = [&](int buf, int mat, int rbase, int ks) -> half8 {
        int r = rbase + (li & 15);
        int cl = ks * 4 + (li >> 4);
        int off = r * 64 + ((cl ^ (r & 7)) << 3);
        return *(const half8*)&lds[g][buf][mat][off];
    };

    auto compute = [&](int buf) {
#pragma unroll
        for (int ks = 0; ks < 2; ++ks) {
            half8 ah0 = rdfrag(buf, 0, wm * 32, ks);
            half8 ah1 = rdfrag(buf, 0, wm * 32 + 16, ks);
            half8 al0 = rdfrag(buf, 1, wm * 32, ks);
            half8 al1 = rdfrag(buf, 1, wm * 32 + 16, ks);
            half8 bh0 = rdfrag(buf, 2, wn * 32, ks);
            half8 bh1 = rdfrag(buf, 2, wn * 32 + 16, ks);
            half8 bl0 = rdfrag(buf, 3, wn * 32, ks);
            half8 bl1 = rdfrag(buf, 3, wn * 32 + 16, ks);
            acc00 = __builtin_amdgcn_mfma_f32_16x16x32_f16(ah0, bh0, acc00, 0, 0, 0);
            acc01 = __builtin_amdgcn_mfma_f32_16x16x32_f16(ah0, bh1, acc01, 0, 0, 0);
            acc10 = __builtin_amdgcn_mfma_f32_16x16x32_f16(ah1, bh0, acc10, 0, 0, 0);
            acc11 = __builtin_amdgcn_mfma_f32_16x16x32_f16(ah1, bh1, acc11, 0, 0, 0);
            acc00 = __builtin_amdgcn_mfma_f32_16x16x32_f16(ah0, bl0, acc00, 0, 0, 0);
            acc01 = __builtin_amdgcn_mfma_f32_16x16x32_f16(ah0, bl1, acc01, 0, 0, 0);
            acc10 = __builtin_amdgcn_mfma_f32_16x16x32_f16(ah1, bl0, acc10, 0, 0, 0);
            acc11 = __builtin_amdgcn_mfma_f32_16x16x32_f16(ah1, bl1, acc11, 0, 0, 0);
            acc00 = __builtin_amdgcn_mfma_f32_16x16x32_f16(al0, bh0, acc00, 0, 0, 0);
            acc01 = __builtin_amdgcn_mfma_f32_16x16x32_f16(al0, bh1, acc01, 0, 0, 0);
            acc10 = __builtin_amdgcn_mfma_f32_16x16x32_f16(al1, bh0, acc10, 0, 0, 0);
            acc11 = __builtin_amdgcn_mfma_f32_16x16x32_f16(al1, bh1, acc11, 0, 0, 0);
        }
    };

    // --- pipelined K loop: 16 k-tiles of BK=64 per group, counted vmcnt ---
    stage4(0, kbase);
#pragma unroll 2
    for (int t = 0; t < 16; ++t) {
        if (t + 1 < 16) {
            stage4((t + 1) & 1, kbase + (t + 1) * 64);
            asm volatile("s_waitcnt vmcnt(8)" ::: "memory");
        } else {
            asm volatile("s_waitcnt vmcnt(0)" ::: "memory");
        }
        __builtin_amdgcn_sched_barrier(0);
        __builtin_amdgcn_s_barrier();
        compute(t & 1);
        __builtin_amdgcn_s_barrier();
    }

    // --- partial-sum exchange: group g keeps the mi==g band, ships the other ---
    f32x4 ship0 = (g == 0) ? acc10 : acc00;
    f32x4 ship1 = (g == 0) ? acc11 : acc01;
    f32x4 keep0 = (g == 0) ? acc00 : acc10;
    f32x4 keep1 = (g == 0) ? acc01 : acc11;
    float4* xch = (float4*)&lds[0][0][0][0];
    {
        int slot0 = ((g * 4 + w4) * 2 + 0) * 64 + li;
        int slot1 = ((g * 4 + w4) * 2 + 1) * 64 + li;
        xch[slot0] = make_float4(ship0[0], ship0[1], ship0[2], ship0[3]);
        xch[slot1] = make_float4(ship1[0], ship1[1], ship1[2], ship1[3]);
    }
    __syncthreads();
    f32x4 fin[2];
    {
        int slot0 = (((1 - g) * 4 + w4) * 2 + 0) * 64 + li;
        int slot1 = (((1 - g) * 4 + w4) * 2 + 1) * 64 + li;
        float4 p0 = xch[slot0];
        float4 p1 = xch[slot1];
        keep0[0] += p0.x; keep0[1] += p0.y; keep0[2] += p0.z; keep0[3] += p0.w;
        keep1[0] += p1.x; keep1[1] += p1.y; keep1[2] += p1.z; keep1[3] += p1.w;
        fin[0] = keep0;
        fin[1] = keep1;
    }

    // --- fused epilogue: each thread finalizes 8 elems (rows wm*32+g*16+..) ---
    const float dt = scal[SC_DT];
    const int lrow = li >> 4, lcol = li & 15;
    const float bias0 = bias[bn * 64 + wn * 32 + lcol];
    const float bias1 = bias[bn * 64 + wn * 32 + 16 + lcol];
    float lerr = 0.0f, lsp = 0.0f;

#pragma unroll
    for (int r = 0; r < 4; ++r) {
        int m = bm * 64 + wm * 32 + g * 16 + lrow * 4 + r;
        size_t base = (size_t)m * DDIM;
#pragma unroll
        for (int ni = 0; ni < 2; ++ni) {
            int n = bn * 64 + wn * 32 + ni * 16 + lcol;
            size_t idx = base + n;
            float accv = fin[ni][r] + (ni == 0 ? bias0 : bias1);
            float xv = xg[idx];
            float lk1 = 0.f, lk2 = 0.f, lk3 = 0.f, lk4 = 0.f, lk5 = 0.f;
            if constexpr (S >= 2) lk1 = gk1[idx];
            if constexpr (S >= 3) lk2 = gk2[idx];
            if constexpr (S >= 4) lk3 = gk3[idx];
            if constexpr (S >= 5) lk4 = gk4[idx];
            if constexpr (S >= 6) lk5 = gk5[idx];
            float xs;
            if constexpr (S == 1) xs = xv;
            if constexpr (S == 2) xs = xv + dt * (0.25f * lk1);
            if constexpr (S == 3)
                xs = xv + dt * ((float)(3.0 / 32.0) * lk1 + (float)(9.0 / 32.0) * lk2);
            if constexpr (S == 4)
                xs = xv + dt * ((float)(1932.0 / 2197.0) * lk1 + (float)(-7200.0 / 2197.0) * lk2 +
                                (float)(7296.0 / 2197.0) * lk3);
            if constexpr (S == 5)
                xs = xv + dt * ((float)(439.0 / 216.0) * lk1 - 8.0f * lk2 +
                                (float)(3680.0 / 513.0) * lk3 + (float)(-845.0 / 4104.0) * lk4);
            if constexpr (S == 6)
                xs = xv + dt * ((float)(-8.0 / 27.0) * lk1 + 2.0f * lk2 +
                                (float)(-3544.0 / 2565.0) * lk3 + (float)(1859.0 / 4104.0) * lk4 +
                                (float)(-11.0 / 40.0) * lk5);
            float sgn = (((int)xs) & 1) ? -1.0f : 1.0f;
            float kv = sgn * accv;
            if constexpr (S < 6) {
                kout[idx] = kv;
                float xn;
                if constexpr (S == 1) xn = xv + dt * (0.25f * kv);
                if constexpr (S == 2)
                    xn = xv + dt * ((float)(3.0 / 32.0) * lk1 + (float)(9.0 / 32.0) * kv);
                if constexpr (S == 3)
                    xn = xv + dt * ((float)(1932.0 / 2197.0) * lk1 +
                                    (float)(-7200.0 / 2197.0) * lk2 + (float)(7296.0 / 2197.0) * kv);
                if constexpr (S == 4)
                    xn = xv + dt * ((float)(439.0 / 216.0) * lk1 - 8.0f * lk2 +
                                    (float)(3680.0 / 513.0) * lk3 + (float)(-845.0 / 4104.0) * kv);
                if constexpr (S == 5)
                    xn = xv + dt * ((float)(-8.0 / 27.0) * lk1 + 2.0f * lk2 +
                                    (float)(-3544.0 / 2565.0) * lk3 +
                                    (float)(1859.0 / 4104.0) * lk4 + (float)(-11.0 / 40.0) * kv);
                float y = reflect_f(xn);
                _Float16 hh, ll;
                split_f16(y, hh, ll);
                Aoh[idx] = hh;
                Aol[idx] = ll;
            } else {
                float x5 = xv + dt * ((float)(16.0 / 135.0) * lk1 + (float)(6656.0 / 12825.0) * lk3 +
                                      (float)(28561.0 / 56430.0) * lk4 + (float)(-9.0 / 50.0) * lk5 +
                                      (float)(2.0 / 55.0) * kv);
                float x4 = xv + dt * ((float)(25.0 / 216.0) * lk1 + (float)(1408.0 / 2565.0) * lk3 +
                                      (float)(2197.0 / 4104.0) * lk4 + (float)(-1.0 / 5.0) * lk5);
                lerr = fmaxf(lerr, fabsf(x5 - x4));
                lsp = fmaxf(lsp, fabsf(x5 - xv));
                x5out[idx] = x5;
            }
        }
    }

    if constexpr (S == 6) {
#pragma unroll
        for (int off = 32; off > 0; off >>= 1) {
            lerr = fmaxf(lerr, __shfl_down(lerr, off));
            lsp = fmaxf(lsp, __shfl_down(lsp, off));
        }
        if (li == 0) {
            serr[wid] = lerr;
            ssp[wid] = lsp;
        }
        __syncthreads();
        if (tid == 0) {
            float e = serr[0], s = ssp[0];
#pragma unroll
            for (int w = 1; w < 8; ++w) {
                e = fmaxf(e, serr[w]);
                s = fmaxf(s, ssp[w]);
            }
            atomicMax((unsigned int*)&scal[SC_ERR], __float_as_uint(e));
            atomicMax((unsigned int*)&scal[SC_SP], __float_as_uint(s));
        }
    }
}

// ---------------- fused scalar update + commit ----------------
// Every block recomputes the deterministic accept decision from the read-parity
// scalar slots; block 0 writes the next-parity slots. Rejected steps skip all
// x/A traffic (x and the Ax split stay valid).

__global__ void commit_fused(float* __restrict__ x, const float* __restrict__ x5,
                             _Float16* __restrict__ Axh, _Float16* __restrict__ Axl,
                             const float* __restrict__ scal_rd, float* __restrict__ scal_wr) {
    float dt = scal_rd[SC_DT];
    float err = scal_rd[SC_ERR];
    float sp = scal_rd[SC_SP];
    unsigned int done = ((const unsigned int*)scal_rd)[SC_DONE];
    bool accept = err < TOLF;
    bool step = accept && (done == 0u);
    float speed = sp / dt;
    unsigned int done_new = (done || (step && speed < SPEED_TOLF)) ? 1u : 0u;
    float scale = 0.9f * powf(TOLF / (err + 1e-12f), 0.2f);
    scale = fminf(fmaxf(scale, 0.1f), 4.0f);
    float dtn = fmaxf(dt * scale, MIN_DTF);
    if (blockIdx.x == 0 && threadIdx.x == 0) {
        scal_wr[SC_DT] = done ? dt : dtn;
        ((unsigned int*)scal_wr)[SC_DONE] = done_new;
        scal_wr[SC_ERR] = 0.0f;
        scal_wr[SC_SP] = 0.0f;
    }
    if (!step) return;  // x unchanged; Ax split still valid
    int tid = blockIdx.x * blockDim.x + threadIdx.x;
    float4* X = (float4*)x;
    const float4* X5 = (const float4*)x5;
    for (int i = tid; i < NV4; i += gridDim.x * blockDim.x) {
        float4 v = X5[i];
        X[i] = v;
        half4v h, l;
        float vv[4] = {v.x, v.y, v.z, v.w};
#pragma unroll
        for (int q = 0; q < 4; ++q) {
            float y = reflect_f(vv[q]);
            _Float16 hh, ll;
            split_f16(y, hh, ll);
            h[q] = hh;
            l[q] = ll;
        }
        *(half4v*)&Axh[(size_t)i * 4] = h;
        *(half4v*)&Axl[(size_t)i * 4] = l;
    }
}

// ---------------- launch ----------------

extern "C" void kernel_launch(void* const* d_in, const int* in_sizes, int n_in, void* d_out,
                              int out_size, void* d_ws, size_t ws_size, hipStream_t stream) {
    const float* x0 = (const float*)d_in[0];
    const float* W = (const float*)d_in[1];
    const float* bias = (const float*)d_in[2];
    float* x = (float*)d_out;

    float* ws = (float*)d_ws;
    float* k1 = ws + 0 * (size_t)NELEM;
    float* k2 = ws + 1 * (size_t)NELEM;
    float* k3 = ws + 2 * (size_t)NELEM;
    float* k4 = ws + 3 * (size_t)NELEM;
    float* k5 = ws + 4 * (size_t)NELEM;
    float* x5 = ws + 5 * (size_t)NELEM;
    float* scal = ws + 6 * (size_t)NELEM;  // 2 parity slots x 8 floats
    _Float16* hb = (_Float16*)(ws + 6 * (size_t)NELEM + 64);
    _Float16* Axh = hb + 0 * (size_t)NELEM;
    _Float16* Axl = hb + 1 * (size_t)NELEM;
    _Float16* P0h = hb + 2 * (size_t)NELEM;
    _Float16* P0l = hb + 3 * (size_t)NELEM;
    _Float16* P1h = hb + 4 * (size_t)NELEM;
    _Float16* P1l = hb + 5 * (size_t)NELEM;
    _Float16* Wh = hb + 6 * (size_t)NELEM;
    _Float16* Wl = Wh + (size_t)DDIM * DDIM;

    wconv_kernel<<<2048, 256, 0, stream>>>(W, Wh, Wl);
    init_kernel<<<1024, 256, 0, stream>>>(x0, x, Axh, Axl, scal);

    for (int it = 0; it < 32; ++it) {
        float* sp = scal + (it & 1) * 8;
        float* sn = scal + ((it + 1) & 1) * 8;
        stage_kernel<1><<<256, 512, 0, stream>>>(Axh, Axl, P0h, P0l, Wh, Wl, bias, x, k1, k2, k3,
                                                 k4, k5, k1, x5, sp);
        stage_kernel<2><<<256, 512, 0, stream>>>(P0h, P0l, P1h, P1l, Wh, Wl, bias, x, k1, k2, k3,
                                                 k4, k5, k2, x5, sp);
        stage_kernel<3><<<256, 512, 0, stream>>>(P1h, P1l, P0h, P0l, Wh, Wl, bias, x, k1, k2, k3,
                                                 k4, k5, k3, x5, sp);
        stage_kernel<4><<<256, 512, 0, stream>>>(P0h, P0l, P1h, P1l, Wh, Wl, bias, x, k1, k2, k3,
                                                 k4, k5, k4, x5, sp);
        stage_kernel<5><<<256, 512, 0, stream>>>(P1h, P1l, P0h, P0l, Wh, Wl, bias, x, k1, k2, k3,
                                                 k4, k5, k5, x5, sp);
        stage_kernel<6><<<256, 512, 0, stream>>>(P0h, P0l, P1h, P1l, Wh, Wl, bias, x, k1, k2, k3,
                                                 k4, k5, k1, x5, sp);
        commit_fused<<<1024, 256, 0, stream>>>(x, x5, Axh, Axl, sp, sn);
    }
}